// Round 17
// baseline (808.582 us; speedup 1.0000x reference)
//
#include <hip/hip_runtime.h>
#include <hip/hip_bf16.h>
#include <cstdint>

#define NB 64        // batch
#define ND 64        // DIM
#define NH 8         // heads
#define DH 64        // dim_head
#define NIN 512      // inner
#define NMLP 256
#define NDEPTH 4
#define NPATCH 225
#define NTOK 226
#define NSB 128      // 2*B (both streams batched)
#define NROWS (NSB*NTOK)   // 28928

#define VP 240       // attention Vt LDS pitch (bf16 units) — R0/R7-validated
#define PBP 40       // P buffer pitch (bf16): 80B rows keep b128 reads 16B-aligned.
                     // R7-validated: conflicts 3.5M -> 1.29M.

// HARD RULE (R3/R4/R5/R8 forensics): no inline asm consuming fresh MFMA output.
// Scalar f2b only.
// R12: occupancy is LDS-pinned; online-softmax chunking only added VALU.
// R13: ROCm erff is cheap; A-S erf cost ~14us. R14: pb double-buffer -3us WIN.

typedef __attribute__((ext_vector_type(8))) short bfrag8;
typedef __attribute__((ext_vector_type(4))) float ffrag4;

// RNE bf16: bit-exact vs __float2bfloat16 for finite inputs, 3 VALU ops.
__device__ __forceinline__ unsigned short f2b(float f) {
  uint32_t u; __builtin_memcpy(&u, &f, 4);
  u += 0x7fff + ((u >> 16) & 1);
  return (unsigned short)(u >> 16);
}

// ---- fused one-shot setup: wconv (blocks 0..2047), dfm (2048..2079),
// build (2080..2335). R12/R13-validated. ----
__global__ __launch_bounds__(256) void k_setup(
    const float* __restrict__ qkv_w, const float* __restrict__ out_w,
    const float* __restrict__ ff_w1, const float* __restrict__ ff_w2,
    const float* __restrict__ fmg_w,
    const float* __restrict__ hsi, const float* __restrict__ lidar,
    const float* __restrict__ cls_h, const float* __restrict__ cls_l,
    const float* __restrict__ pos_h, const float* __restrict__ pos_l,
    const float* __restrict__ g, const float* __restrict__ bb,
    uint16_t* __restrict__ Wqv, uint16_t* __restrict__ Wo,
    uint16_t* __restrict__ W1, uint16_t* __restrict__ W2,
    float* __restrict__ sdfm, float* __restrict__ X, uint16_t* __restrict__ Xn) {
  __shared__ float Xt[113][65];        // build staging (29,380 B)
  __shared__ float xc[2][128];         // dfm means
  int blk = blockIdx.x, t = threadIdx.x;

  if (blk < 2048) {
    // ---- weight convert+transpose (R7-validated addressing) ----
    int i = blk * 256 + t;             // covers 524288
    if (i < 262144) {
      int ly = i >> 16, rem = i & 65535, n = rem >> 6, k = rem & 63;
      int col = n + ((n >> 9) << 9);   // n<512 ? q col n : v col n+512
      Wqv[i] = f2b(qkv_w[((size_t)ly * 64 + k) * 1536 + col]);
    } else if (i < 393216) {
      int j = i - 262144;
      int ly = j >> 15, rem = j & 32767, n = rem >> 9, k = rem & 511;
      Wo[j] = f2b(out_w[((size_t)ly * 512 + k) * 64 + n]);
    } else if (i < 458752) {
      int j = i - 393216;
      int ly = j >> 14, rem = j & 16383, n = rem >> 6, k = rem & 63;
      W1[j] = f2b(ff_w1[((size_t)ly * 64 + k) * 256 + n]);
    } else {
      int j = i - 458752;
      int ly = j >> 14, rem = j & 16383, n = rem >> 8, k = rem & 255;
      W2[j] = f2b(ff_w2[((size_t)ly * 256 + k) * 64 + n]);
    }
  } else if (blk < 2080) {
    // ---- fusion-matrix diagonal (2 batches per block) ----
    int gsel = t >> 7, tt = t & 127;
    int b = (blk - 2048) * 2 + gsel;
    const float* src = (tt < 64) ? hsi : lidar;
    int d = tt & 63;
    const float* p = src + ((size_t)b * 64 + d) * NPATCH;
    float s = 0.f;
    for (int i = 0; i < NPATCH; ++i) s += p[i];
    xc[gsel][tt] = s * (1.0f / 225.0f);
    __syncthreads();
    if (tt < 64) {
      float acc = 0.f;
      const float* w = fmg_w + tt * 65;   // column 65*tt of [128,4096]
      for (int c = 0; c < 128; ++c) acc += xc[gsel][c] * w[c * 4096];
      float sg = 1.0f / (1.0f + expf(-acc));
      sdfm[b * 64 + tt] = sqrtf(sg);
    }
  } else {
    // ---- build X + Xn (R10-validated coalesced version) ----
    int bidx = blk - 2080;               // 0..255
    int sb = bidx >> 1, h = bidx & 1;
    int s = sb >> 6, b = sb & 63;
    int w = t >> 6, l = t & 63;
    int p0 = h ? 112 : 0;
    int pc = h ? 113 : 112;
    for (int dd = 0; dd < 16; ++dd) {
      int d = w * 16 + dd;
      const float* row = hsi + ((size_t)b * 64 + d) * NPATCH + p0;
      #pragma unroll
      for (int ch = 0; ch < 2; ++ch) {
        int i = ch * 64 + l;
        if (i < pc) Xt[i][d] = row[i];
      }
    }
    __syncthreads();
    int d = l;
    for (int n_loc = w; n_loc <= 112; n_loc += 4) {
      int n = h * 113 + n_loc;
      float v;
      if (n == 0) v = s ? cls_l[d] : cls_h[d];
      else        v = Xt[h ? n_loc : (n_loc - 1)][d];
      v += (s ? pos_l : pos_h)[n * ND + d];
      size_t r = (size_t)sb * NTOK + n;
      X[r * ND + d] = v;
      float sm = v, sq = v * v;
      #pragma unroll
      for (int o = 32; o; o >>= 1) { sm += __shfl_xor(sm, o); sq += __shfl_xor(sq, o); }
      float m = sm * (1.f / 64.f);
      float rs = rsqrtf(sq * (1.f / 64.f) - m * m + 1e-5f);
      Xn[r * ND + d] = f2b((v - m) * rs * g[d] + bb[d]);
    }
  }
}

// ---- fused QV-projection + MFMA attention: R14 structure (48.4us) + two
// refinements: (1) XCD-aware block relabel h=bh>>7, sb=bh&127 — all 8 head
// blocks of an sb share B mod 8 -> same XCD L2 -> Xn fetched once per XCD;
// (2) tree-shaped softmax max/sum (depth 4 vs 14 serial — max exact, sum
// reassoc benign per R9's validated kc-parity split).
// LDS = 30720 (qs) + 30720 (vt) + 20480 (pb dbuf) = 81920 B = 2 blocks/CU.
__global__ __launch_bounds__(512) void k_fattn(const uint16_t* __restrict__ Xn,
    const uint16_t* __restrict__ Wqv,   // [1024][64] this layer
    const float* __restrict__ sdfm, uint16_t* __restrict__ Og) {
  __shared__ __align__(16) uint16_t qs[240 * 64];
  __shared__ __align__(16) uint16_t vt[64 * VP];
  __shared__ __align__(16) uint16_t pb[8][2][16 * PBP];
  int bh = blockIdx.x;
  int sb = bh & 127, h = bh >> 7;      // XCD swizzle: same sb -> same B%8
  int t = threadIdx.x, w = t >> 6, l = t & 63;
  int quad = l >> 4, c = l & 15;
  const uint16_t* Xb = Xn + (size_t)sb * NTOK * ND;

  float sf[4];
  #pragma unroll
  for (int dt = 0; dt < 4; ++dt)
    sf[dt] = sdfm[(sb & 63) * 64 + dt * 16 + c] * 0.35355339059327373f;  // sqrt(1/8)

  // phase 1: Q,V projection for this head (8-way wave split) — R7-frozen
  for (int it = w; it < 15; it += 8) {
    int i0 = it * 16;
    int ri = i0 + c; if (ri > 225) ri = 225;
    bfrag8 a0 = *(const bfrag8*)(Xb + (size_t)ri * 64 + quad * 8);
    bfrag8 a1 = *(const bfrag8*)(Xb + (size_t)ri * 64 + 32 + quad * 8);
    #pragma unroll
    for (int dt = 0; dt < 4; ++dt) {
      int nq = h * 64 + dt * 16 + c;
      bfrag8 bq0 = *(const bfrag8*)(Wqv + (size_t)nq * 64 + quad * 8);
      bfrag8 bq1 = *(const bfrag8*)(Wqv + (size_t)nq * 64 + 32 + quad * 8);
      ffrag4 zq = {0.f, 0.f, 0.f, 0.f};
      zq = __builtin_amdgcn_mfma_f32_16x16x32_bf16(a0, bq0, zq, 0, 0, 0);
      zq = __builtin_amdgcn_mfma_f32_16x16x32_bf16(a1, bq1, zq, 0, 0, 0);
      bfrag8 bv0 = *(const bfrag8*)(Wqv + (size_t)(512 + nq) * 64 + quad * 8);
      bfrag8 bv1 = *(const bfrag8*)(Wqv + (size_t)(512 + nq) * 64 + 32 + quad * 8);
      ffrag4 zv = {0.f, 0.f, 0.f, 0.f};
      zv = __builtin_amdgcn_mfma_f32_16x16x32_bf16(a0, bv0, zv, 0, 0, 0);
      zv = __builtin_amdgcn_mfma_f32_16x16x32_bf16(a1, bv1, zv, 0, 0, 0);
      int d = dt * 16 + c;
      #pragma unroll
      for (int r = 0; r < 4; ++r) {
        int i = i0 + quad * 4 + r;
        qs[i * 64 + ((((d >> 3) ^ (i & 7))) << 3) + (d & 7)] = f2b(zq[r] * sf[dt]);
        vt[d * VP + i] = f2b(zv[r]);
      }
    }
  }
  __syncthreads();

  for (int it = w; it < 15; it += 8) {
    int i0 = it * 16;
    int ra = i0 + c, sa = ra & 7;
    bfrag8 a0 = *(const bfrag8*)(qs + ra * 64 + ((quad ^ sa) << 3));
    bfrag8 a1 = *(const bfrag8*)(qs + ra * 64 + (((quad + 4) ^ sa) << 3));
    ffrag4 acc[15];
    #pragma unroll
    for (int jt = 0; jt < 15; ++jt) {
      int rb = jt * 16 + c, sk = rb & 7;
      bfrag8 b0 = *(const bfrag8*)(qs + rb * 64 + ((quad ^ sk) << 3));
      bfrag8 b1 = *(const bfrag8*)(qs + rb * 64 + (((quad + 4) ^ sk) << 3));
      ffrag4 z = {0.f, 0.f, 0.f, 0.f};
      z = __builtin_amdgcn_mfma_f32_16x16x32_bf16(a0, b0, z, 0, 0, 0);
      z = __builtin_amdgcn_mfma_f32_16x16x32_bf16(a1, b1, z, 0, 0, 0);
      acc[jt] = z;
    }
    // softmax: store raw E = exp(S - m); 1/l applied at O store.
    // Tree reductions (depth 4) instead of 14-deep serial chains.
    float rinv[4];
    #pragma unroll
    for (int r = 0; r < 4; ++r) {
      float t0 = fmaxf(acc[0][r],  acc[1][r]);
      float t1 = fmaxf(acc[2][r],  acc[3][r]);
      float t2 = fmaxf(acc[4][r],  acc[5][r]);
      float t3 = fmaxf(acc[6][r],  acc[7][r]);
      float t4 = fmaxf(acc[8][r],  acc[9][r]);
      float t5 = fmaxf(acc[10][r], acc[11][r]);
      float t6 = fmaxf(acc[12][r], acc[13][r]);
      float m = fmaxf(fmaxf(fmaxf(t0, t1), fmaxf(t2, t3)),
                      fmaxf(fmaxf(t4, t5), fmaxf(t6, acc[14][r])));
      #pragma unroll
      for (int o = 8; o; o >>= 1) m = fmaxf(m, __shfl_xor(m, o));
      float e[15];
      #pragma unroll
      for (int jt = 0; jt < 15; ++jt) {
        float p = __expf(acc[jt][r] - m);
        if (jt == 14 && c >= 2) p = 0.f;   // j = 224+c >= 226 invalid (dup rows)
        e[jt] = p;
        acc[jt][r] = p;
      }
      float s = (((e[0] + e[1]) + (e[2] + e[3])) + ((e[4] + e[5]) + (e[6] + e[7])))
              + (((e[8] + e[9]) + (e[10] + e[11])) + ((e[12] + e[13]) + e[14]));
      #pragma unroll
      for (int o = 8; o; o >>= 1) s += __shfl_xor(s, o);
      rinv[r] = 1.f / s;
    }
    ffrag4 oa[4];
    #pragma unroll
    for (int dt = 0; dt < 4; ++dt) oa[dt] = (ffrag4){0.f, 0.f, 0.f, 0.f};
    for (int jc = 0; jc < 8; ++jc) {
      uint16_t* pw = &pb[w][jc & 1][0];   // double-buffer: no WAR across jc
      if (jc == 7) {
        *(unsigned long long*)(pw + c * PBP + 16 + quad * 4) = 0ull;  // zero E cols 16..31
      }
      #pragma unroll
      for (int r = 0; r < 4; ++r) {
        int row = quad * 4 + r;
        pw[row * PBP + c] = f2b(acc[2 * jc][r]);
        if (jc < 7) pw[row * PBP + 16 + c] = f2b(acc[2 * jc + 1][r]);
      }
      bfrag8 pa = *(const bfrag8*)(pw + c * PBP + quad * 8);  // byte 80c+16q: 16B-aligned
      int j0 = jc * 32;
      #pragma unroll
      for (int dt = 0; dt < 4; ++dt) {
        bfrag8 vb;
        if (jc < 7)
          vb = *(const bfrag8*)(vt + (dt * 16 + c) * VP + j0 + quad * 8);
        else
          vb = *(const bfrag8*)(vt + (dt * 16 + c) * VP + 224 + (quad & 1) * 8);
        oa[dt] = __builtin_amdgcn_mfma_f32_16x16x32_bf16(pa, vb, oa[dt], 0, 0, 0);
      }
    }
    #pragma unroll
    for (int dt = 0; dt < 4; ++dt) {
      #pragma unroll
      for (int r = 0; r < 4; ++r) {
        int i = i0 + quad * 4 + r;
        if (i < NTOK)
          Og[((size_t)sb * NTOK + i) * NIN + h * DH + dt * 16 + c] =
              f2b(oa[dt][r] * rinv[r]);
      }
    }
  }
}

// ---- merged proj+FF: 2 waves per 16-row tile — BYTE-EXACT R10 (erff) ----
__global__ __launch_bounds__(128) void k_pf(const uint16_t* __restrict__ Og,
    const uint16_t* __restrict__ Wot,   // [64][512] bf16
    const float* __restrict__ bo, float* __restrict__ X,
    const float* __restrict__ g2, const float* __restrict__ bb2,
    const uint16_t* __restrict__ W1t,   // [256][64] bf16
    const float* __restrict__ b1,
    const uint16_t* __restrict__ W2t,   // [64][256] bf16
    const float* __restrict__ b2,
    const float* __restrict__ gn, const float* __restrict__ bbn,
    uint16_t* __restrict__ XnOut) {
  __shared__ __align__(16) uint16_t xa2[16 * 72];    // 2304 B
  __shared__ __align__(16) uint16_t ha[16 * 264];    // 8448 B
  __shared__ float lnp[2][16][2];                    // 256 B: [wave][row][s,q]
  int t = threadIdx.x;                 // 128 = 2 waves
  int w = t >> 6, l = t & 63;
  int quad = l >> 4, c = l & 15;
  int r0 = blockIdx.x * 16;

  // ---- proj part: wave w computes jt in {2w, 2w+1} ----
  const uint16_t* orow = Og + (size_t)(r0 + c) * 512 + quad * 8;
  bfrag8 a[16];
  #pragma unroll
  for (int kc = 0; kc < 16; ++kc) a[kc] = *(const bfrag8*)(orow + kc * 32);
  ffrag4 acc[2][2];                    // [jt_local][kc parity] -> chains of 8
  #pragma unroll
  for (int j = 0; j < 2; ++j)
    #pragma unroll
    for (int p = 0; p < 2; ++p) acc[j][p] = (ffrag4){0.f, 0.f, 0.f, 0.f};
  #pragma unroll
  for (int kc = 0; kc < 16; ++kc) {
    #pragma unroll
    for (int j = 0; j < 2; ++j) {
      int jt = 2 * w + j;
      bfrag8 b = *(const bfrag8*)(Wot + (size_t)(jt * 16 + c) * 512 + kc * 32 + quad * 8);
      acc[j][kc & 1] = __builtin_amdgcn_mfma_f32_16x16x32_bf16(a[kc], b, acc[j][kc & 1], 0, 0, 0);
    }
  }
  float xv[2][4];
  #pragma unroll
  for (int j = 0; j < 2; ++j) {
    int jt = 2 * w + j;
    float bv = bo[jt * 16 + c];
    #pragma unroll
    for (int r = 0; r < 4; ++r) {
      int il = quad * 4 + r;
      size_t idx = (size_t)(r0 + il) * 64 + jt * 16 + c;
      xv[j][r] = X[idx] + (acc[j][0][r] + acc[j][1][r]) + bv;   // X write deferred to FF2
    }
  }
  #pragma unroll
  for (int r = 0; r < 4; ++r) {
    float s = xv[0][r] + xv[1][r];
    float q = xv[0][r] * xv[0][r] + xv[1][r] * xv[1][r];
    #pragma unroll
    for (int o = 8; o; o >>= 1) { s += __shfl_xor(s, o); q += __shfl_xor(q, o); }
    if (c == 0) { lnp[w][quad * 4 + r][0] = s; lnp[w][quad * 4 + r][1] = q; }
  }
  __syncthreads();
  #pragma unroll
  for (int r = 0; r < 4; ++r) {
    int il = quad * 4 + r;
    float s = lnp[0][il][0] + lnp[1][il][0];
    float q = lnp[0][il][1] + lnp[1][il][1];
    float m = s * (1.f / 64.f);
    float rs = rsqrtf(q * (1.f / 64.f) - m * m + 1e-5f);
    #pragma unroll
    for (int j = 0; j < 2; ++j) {
      int n = (2 * w + j) * 16 + c;
      xa2[il * 72 + n] = f2b((xv[j][r] - m) * rs * g2[n] + bb2[n]);
    }
  }
  __syncthreads();
  // ---- FF1: wave w computes h-cols jt in {8w .. 8w+7} ----
  const uint16_t* xrow = xa2 + c * 72;
  bfrag8 a0 = *(const bfrag8*)(xrow + quad * 8);
  bfrag8 a1 = *(const bfrag8*)(xrow + 32 + quad * 8);
  #pragma unroll
  for (int jj = 0; jj < 8; ++jj) {
    int jt = 8 * w + jj;
    bfrag8 b0  = *(const bfrag8*)(W1t + (size_t)(jt * 16 + c) * 64 + quad * 8);
    bfrag8 b1f = *(const bfrag8*)(W1t + (size_t)(jt * 16 + c) * 64 + 32 + quad * 8);
    ffrag4 z = {0.f, 0.f, 0.f, 0.f};
    z = __builtin_amdgcn_mfma_f32_16x16x32_bf16(a0, b0, z, 0, 0, 0);
    z = __builtin_amdgcn_mfma_f32_16x16x32_bf16(a1, b1f, z, 0, 0, 0);
    float bv = b1[jt * 16 + c];
    #pragma unroll
    for (int r = 0; r < 4; ++r) {
      float zz = z[r] + bv;
      float hg = 0.5f * zz * (1.f + erff(zz * 0.7071067811865476f));
      ha[(quad * 4 + r) * 264 + jt * 16 + c] = f2b(hg);
    }
  }
  __syncthreads();
  // ---- FF2: wave w computes out cols jt in {2w, 2w+1} ----
  ffrag4 o2[2][2];
  #pragma unroll
  for (int j = 0; j < 2; ++j)
    #pragma unroll
    for (int p = 0; p < 2; ++p) o2[j][p] = (ffrag4){0.f, 0.f, 0.f, 0.f};
  #pragma unroll
  for (int kc = 0; kc < 8; ++kc) {
    bfrag8 pa = *(const bfrag8*)(ha + c * 264 + kc * 32 + quad * 8);
    #pragma unroll
    for (int j = 0; j < 2; ++j) {
      int jt = 2 * w + j;
      bfrag8 vb = *(const bfrag8*)(W2t + (size_t)(jt * 16 + c) * 256 + kc * 32 + quad * 8);
      o2[j][kc & 1] = __builtin_amdgcn_mfma_f32_16x16x32_bf16(pa, vb, o2[j][kc & 1], 0, 0, 0);
    }
  }
  float yv[2][4];
  #pragma unroll
  for (int j = 0; j < 2; ++j) {
    int jt = 2 * w + j;
    float bv = b2[jt * 16 + c];
    #pragma unroll
    for (int r = 0; r < 4; ++r) {
      int il = quad * 4 + r;
      size_t idx = (size_t)(r0 + il) * 64 + jt * 16 + c;
      float v = xv[j][r] + (o2[j][0][r] + o2[j][1][r]) + bv;    // residual from regs
      X[idx] = v;
      yv[j][r] = v;
    }
  }
  #pragma unroll
  for (int r = 0; r < 4; ++r) {
    float s = yv[0][r] + yv[1][r];
    float q = yv[0][r] * yv[0][r] + yv[1][r] * yv[1][r];
    #pragma unroll
    for (int o = 8; o; o >>= 1) { s += __shfl_xor(s, o); q += __shfl_xor(q, o); }
    if (c == 0) { lnp[w][quad * 4 + r][0] = s; lnp[w][quad * 4 + r][1] = q; }
  }
  __syncthreads();
  #pragma unroll
  for (int r = 0; r < 4; ++r) {
    int il = quad * 4 + r;
    float s = lnp[0][il][0] + lnp[1][il][0];
    float q = lnp[0][il][1] + lnp[1][il][1];
    float m = s * (1.f / 64.f);
    float rs = rsqrtf(q * (1.f / 64.f) - m * m + 1e-5f);
    #pragma unroll
    for (int j = 0; j < 2; ++j) {
      int n = (2 * w + j) * 16 + c;
      XnOut[(size_t)(r0 + il) * 64 + n] = f2b((yv[j][r] - m) * rs * gn[n] + bbn[n]);
    }
  }
}

// ---- swap cls tokens between streams; refresh Xn (LN1 layer0) for those rows ----
__global__ void k_xchg(float* __restrict__ X, uint16_t* __restrict__ Xn,
                       const float* __restrict__ g, const float* __restrict__ bb) {
  int b = blockIdx.x, d = threadIdx.x;   // 64 blocks x 64 threads (1 wave)
  size_t i0 = (size_t)(b * NTOK) * ND + d;
  size_t i1 = (size_t)((64 + b) * NTOK) * ND + d;
  float a = X[i0], cc = X[i1];
  X[i0] = cc; X[i1] = a;
  float s0 = cc, q0 = cc * cc, s1 = a, q1 = a * a;
  #pragma unroll
  for (int o = 32; o; o >>= 1) {
    s0 += __shfl_xor(s0, o); q0 += __shfl_xor(q0, o);
    s1 += __shfl_xor(s1, o); q1 += __shfl_xor(q1, o);
  }
  float m0 = s0 * (1.f / 64.f), rs0 = rsqrtf(q0 * (1.f / 64.f) - m0 * m0 + 1e-5f);
  float m1 = s1 * (1.f / 64.f), rs1 = rsqrtf(q1 * (1.f / 64.f) - m1 * m1 + 1e-5f);
  Xn[i0] = f2b((cc - m0) * rs0 * g[d] + bb[d]);
  Xn[i1] = f2b((a - m1) * rs1 * g[d] + bb[d]);
}

// ---- final: out = h_cls + l_cls ----
__global__ void k_out(const float* __restrict__ X, float* __restrict__ out) {
  int i = blockIdx.x * 64 + threadIdx.x;
  int b = i >> 6, d = i & 63;
  out[i] = X[(size_t)b * NTOK * ND + d] + X[(size_t)(64 + b) * NTOK * ND + d];
}

extern "C" void kernel_launch(void* const* d_in, const int* in_sizes, int n_in,
                              void* d_out, int out_size, void* d_ws, size_t ws_size,
                              hipStream_t stream) {
  const float* hsi   = (const float*)d_in[0];
  const float* lidar = (const float*)d_in[1];
  const float* cls_h = (const float*)d_in[2];
  const float* cls_l = (const float*)d_in[3];
  const float* pos_h = (const float*)d_in[4];
  const float* pos_l = (const float*)d_in[5];
  const float* fmg_w = (const float*)d_in[6];
  const float* ln1_g = (const float*)d_in[7];
  const float* ln1_b = (const float*)d_in[8];
  const float* qkv_w = (const float*)d_in[9];
  const float* out_w = (const float*)d_in[10];
  const float* out_b = (const float*)d_in[11];
  const float* ln2_g = (const float*)d_in[12];
  const float* ln2_b = (const float*)d_in[13];
  const float* ff_w1 = (const float*)d_in[14];
  const float* ff_b1 = (const float*)d_in[15];
  const float* ff_w2 = (const float*)d_in[16];
  const float* ff_b2 = (const float*)d_in[17];

  char* ws = (char*)d_ws;
  float*    X    = (float*)ws;                       // 7,405,568 B
  float*    sdfm = (float*)(ws + 7405568);           // 16,384 B
  uint16_t* Xn   = (uint16_t*)(ws + 7421952);        // 3,702,784 B
  uint16_t* Og   = (uint16_t*)(ws + 11124736);       // 29,622,272 B
  uint16_t* Wqv  = (uint16_t*)(ws + 40747008);       // 524,288 B
  uint16_t* Wo   = (uint16_t*)(ws + 41271296);       // 262,144 B
  uint16_t* W1   = (uint16_t*)(ws + 41533440);       // 131,072 B
  uint16_t* W2   = (uint16_t*)(ws + 41664512);       // 131,072 B -> end 41,795,584

  k_setup<<<2336, 256, 0, stream>>>(qkv_w, out_w, ff_w1, ff_w2, fmg_w,
                                    hsi, lidar, cls_h, cls_l, pos_h, pos_l,
                                    ln1_g, ln1_b,
                                    Wqv, Wo, W1, W2, sdfm, X, Xn);
  for (int pass = 0; pass < 2; ++pass) {
    for (int ly = 0; ly < NDEPTH; ++ly) {
      int nx = (ly + 1) & 3;   // next layer's LN1 params (harmless on final layer)
      k_fattn<<<NSB * NH, 512, 0, stream>>>(Xn, Wqv + (size_t)ly * 65536, sdfm, Og);
      k_pf<<<NROWS / 16, 128, 0, stream>>>(Og, Wo + (size_t)ly * 32768, out_b + ly * ND,
                                           X, ln2_g + ly * ND, ln2_b + ly * ND,
                                           W1 + (size_t)ly * 16384, ff_b1 + ly * NMLP,
                                           W2 + (size_t)ly * 16384, ff_b2 + ly * ND,
                                           ln1_g + nx * ND, ln1_b + nx * ND, Xn);
    }
    if (pass == 0) k_xchg<<<64, 64, 0, stream>>>(X, Xn, ln1_g, ln1_b);
  }
  k_out<<<64, 64, 0, stream>>>(X, (float*)d_out);
}

// Round 18
// 792.917 us; speedup vs baseline: 1.0198x; 1.0198x over previous
//
#include <hip/hip_runtime.h>
#include <hip/hip_bf16.h>
#include <cstdint>

#define NB 64        // batch
#define ND 64        // DIM
#define NH 8         // heads
#define DH 64        // dim_head
#define NIN 512      // inner
#define NMLP 256
#define NDEPTH 4
#define NPATCH 225
#define NTOK 226
#define NSB 128      // 2*B (both streams batched)
#define NROWS (NSB*NTOK)   // 28928

#define VP 240       // attention Vt LDS pitch (bf16 units) — R0/R7-validated
#define PBP 40       // P buffer pitch (bf16): 80B rows keep b128 reads 16B-aligned.
                     // R7-validated: conflicts 3.5M -> 1.29M.

// HARD RULE (R3/R4/R5/R8 forensics): no inline asm consuming fresh MFMA output.
// Scalar f2b only.
// R12: occupancy is LDS-pinned; online-softmax chunking only added VALU.
// R13: ROCm erff is cheap; A-S erf cost ~14us. R14: pb double-buffer -3us WIN.
// R17: tree-softmax + XCD swizzle REGRESSED (48.4 -> 51.8us; FETCH 14.7 -> 2.4MB
// proved the swizzle works but HBM was never the limiter). This is the byte-exact
// R14 configuration — measured best: 793.9us total, k_fattn 48.4us.

typedef __attribute__((ext_vector_type(8))) short bfrag8;
typedef __attribute__((ext_vector_type(4))) float ffrag4;

// RNE bf16: bit-exact vs __float2bfloat16 for finite inputs, 3 VALU ops.
__device__ __forceinline__ unsigned short f2b(float f) {
  uint32_t u; __builtin_memcpy(&u, &f, 4);
  u += 0x7fff + ((u >> 16) & 1);
  return (unsigned short)(u >> 16);
}

// ---- fused one-shot setup: wconv (blocks 0..2047), dfm (2048..2079),
// build (2080..2335). R12/R13-validated. ----
__global__ __launch_bounds__(256) void k_setup(
    const float* __restrict__ qkv_w, const float* __restrict__ out_w,
    const float* __restrict__ ff_w1, const float* __restrict__ ff_w2,
    const float* __restrict__ fmg_w,
    const float* __restrict__ hsi, const float* __restrict__ lidar,
    const float* __restrict__ cls_h, const float* __restrict__ cls_l,
    const float* __restrict__ pos_h, const float* __restrict__ pos_l,
    const float* __restrict__ g, const float* __restrict__ bb,
    uint16_t* __restrict__ Wqv, uint16_t* __restrict__ Wo,
    uint16_t* __restrict__ W1, uint16_t* __restrict__ W2,
    float* __restrict__ sdfm, float* __restrict__ X, uint16_t* __restrict__ Xn) {
  __shared__ float Xt[113][65];        // build staging (29,380 B)
  __shared__ float xc[2][128];         // dfm means
  int blk = blockIdx.x, t = threadIdx.x;

  if (blk < 2048) {
    // ---- weight convert+transpose (R7-validated addressing) ----
    int i = blk * 256 + t;             // covers 524288
    if (i < 262144) {
      int ly = i >> 16, rem = i & 65535, n = rem >> 6, k = rem & 63;
      int col = n + ((n >> 9) << 9);   // n<512 ? q col n : v col n+512
      Wqv[i] = f2b(qkv_w[((size_t)ly * 64 + k) * 1536 + col]);
    } else if (i < 393216) {
      int j = i - 262144;
      int ly = j >> 15, rem = j & 32767, n = rem >> 9, k = rem & 511;
      Wo[j] = f2b(out_w[((size_t)ly * 512 + k) * 64 + n]);
    } else if (i < 458752) {
      int j = i - 393216;
      int ly = j >> 14, rem = j & 16383, n = rem >> 6, k = rem & 63;
      W1[j] = f2b(ff_w1[((size_t)ly * 64 + k) * 256 + n]);
    } else {
      int j = i - 458752;
      int ly = j >> 14, rem = j & 16383, n = rem >> 8, k = rem & 255;
      W2[j] = f2b(ff_w2[((size_t)ly * 256 + k) * 64 + n]);
    }
  } else if (blk < 2080) {
    // ---- fusion-matrix diagonal (2 batches per block) ----
    int gsel = t >> 7, tt = t & 127;
    int b = (blk - 2048) * 2 + gsel;
    const float* src = (tt < 64) ? hsi : lidar;
    int d = tt & 63;
    const float* p = src + ((size_t)b * 64 + d) * NPATCH;
    float s = 0.f;
    for (int i = 0; i < NPATCH; ++i) s += p[i];
    xc[gsel][tt] = s * (1.0f / 225.0f);
    __syncthreads();
    if (tt < 64) {
      float acc = 0.f;
      const float* w = fmg_w + tt * 65;   // column 65*tt of [128,4096]
      for (int c = 0; c < 128; ++c) acc += xc[gsel][c] * w[c * 4096];
      float sg = 1.0f / (1.0f + expf(-acc));
      sdfm[b * 64 + tt] = sqrtf(sg);
    }
  } else {
    // ---- build X + Xn (R10-validated coalesced version) ----
    int bidx = blk - 2080;               // 0..255
    int sb = bidx >> 1, h = bidx & 1;
    int s = sb >> 6, b = sb & 63;
    int w = t >> 6, l = t & 63;
    int p0 = h ? 112 : 0;
    int pc = h ? 113 : 112;
    for (int dd = 0; dd < 16; ++dd) {
      int d = w * 16 + dd;
      const float* row = hsi + ((size_t)b * 64 + d) * NPATCH + p0;
      #pragma unroll
      for (int ch = 0; ch < 2; ++ch) {
        int i = ch * 64 + l;
        if (i < pc) Xt[i][d] = row[i];
      }
    }
    __syncthreads();
    int d = l;
    for (int n_loc = w; n_loc <= 112; n_loc += 4) {
      int n = h * 113 + n_loc;
      float v;
      if (n == 0) v = s ? cls_l[d] : cls_h[d];
      else        v = Xt[h ? n_loc : (n_loc - 1)][d];
      v += (s ? pos_l : pos_h)[n * ND + d];
      size_t r = (size_t)sb * NTOK + n;
      X[r * ND + d] = v;
      float sm = v, sq = v * v;
      #pragma unroll
      for (int o = 32; o; o >>= 1) { sm += __shfl_xor(sm, o); sq += __shfl_xor(sq, o); }
      float m = sm * (1.f / 64.f);
      float rs = rsqrtf(sq * (1.f / 64.f) - m * m + 1e-5f);
      Xn[r * ND + d] = f2b((v - m) * rs * g[d] + bb[d]);
    }
  }
}

// ---- fused QV-projection + MFMA attention: R7/R9 structure with pb
// double-buffered (half = jc&1) — R14-validated WIN (51.4 -> 48.4us).
// LDS = 30720 (qs) + 30720 (vt) + 20480 (pb) = 81920 B = exactly 2 blocks/CU.
__global__ __launch_bounds__(512) void k_fattn(const uint16_t* __restrict__ Xn,
    const uint16_t* __restrict__ Wqv,   // [1024][64] this layer
    const float* __restrict__ sdfm, uint16_t* __restrict__ Og) {
  __shared__ __align__(16) uint16_t qs[240 * 64];
  __shared__ __align__(16) uint16_t vt[64 * VP];
  __shared__ __align__(16) uint16_t pb[8][2][16 * PBP];
  int bh = blockIdx.x;
  int sb = bh >> 3, h = bh & 7;
  int t = threadIdx.x, w = t >> 6, l = t & 63;
  int quad = l >> 4, c = l & 15;
  const uint16_t* Xb = Xn + (size_t)sb * NTOK * ND;

  float sf[4];
  #pragma unroll
  for (int dt = 0; dt < 4; ++dt)
    sf[dt] = sdfm[(sb & 63) * 64 + dt * 16 + c] * 0.35355339059327373f;  // sqrt(1/8)

  // phase 1: Q,V projection for this head (8-way wave split) — R7-frozen
  for (int it = w; it < 15; it += 8) {
    int i0 = it * 16;
    int ri = i0 + c; if (ri > 225) ri = 225;
    bfrag8 a0 = *(const bfrag8*)(Xb + (size_t)ri * 64 + quad * 8);
    bfrag8 a1 = *(const bfrag8*)(Xb + (size_t)ri * 64 + 32 + quad * 8);
    #pragma unroll
    for (int dt = 0; dt < 4; ++dt) {
      int nq = h * 64 + dt * 16 + c;
      bfrag8 bq0 = *(const bfrag8*)(Wqv + (size_t)nq * 64 + quad * 8);
      bfrag8 bq1 = *(const bfrag8*)(Wqv + (size_t)nq * 64 + 32 + quad * 8);
      ffrag4 zq = {0.f, 0.f, 0.f, 0.f};
      zq = __builtin_amdgcn_mfma_f32_16x16x32_bf16(a0, bq0, zq, 0, 0, 0);
      zq = __builtin_amdgcn_mfma_f32_16x16x32_bf16(a1, bq1, zq, 0, 0, 0);
      bfrag8 bv0 = *(const bfrag8*)(Wqv + (size_t)(512 + nq) * 64 + quad * 8);
      bfrag8 bv1 = *(const bfrag8*)(Wqv + (size_t)(512 + nq) * 64 + 32 + quad * 8);
      ffrag4 zv = {0.f, 0.f, 0.f, 0.f};
      zv = __builtin_amdgcn_mfma_f32_16x16x32_bf16(a0, bv0, zv, 0, 0, 0);
      zv = __builtin_amdgcn_mfma_f32_16x16x32_bf16(a1, bv1, zv, 0, 0, 0);
      int d = dt * 16 + c;
      #pragma unroll
      for (int r = 0; r < 4; ++r) {
        int i = i0 + quad * 4 + r;
        qs[i * 64 + ((((d >> 3) ^ (i & 7))) << 3) + (d & 7)] = f2b(zq[r] * sf[dt]);
        vt[d * VP + i] = f2b(zv[r]);
      }
    }
  }
  __syncthreads();

  for (int it = w; it < 15; it += 8) {
    int i0 = it * 16;
    int ra = i0 + c, sa = ra & 7;
    bfrag8 a0 = *(const bfrag8*)(qs + ra * 64 + ((quad ^ sa) << 3));
    bfrag8 a1 = *(const bfrag8*)(qs + ra * 64 + (((quad + 4) ^ sa) << 3));
    ffrag4 acc[15];
    #pragma unroll
    for (int jt = 0; jt < 15; ++jt) {
      int rb = jt * 16 + c, sk = rb & 7;
      bfrag8 b0 = *(const bfrag8*)(qs + rb * 64 + ((quad ^ sk) << 3));
      bfrag8 b1 = *(const bfrag8*)(qs + rb * 64 + (((quad + 4) ^ sk) << 3));
      ffrag4 z = {0.f, 0.f, 0.f, 0.f};
      z = __builtin_amdgcn_mfma_f32_16x16x32_bf16(a0, b0, z, 0, 0, 0);
      z = __builtin_amdgcn_mfma_f32_16x16x32_bf16(a1, b1, z, 0, 0, 0);
      acc[jt] = z;
    }
    // softmax: store raw E = exp(S - m); 1/l applied at O store
    float rinv[4];
    #pragma unroll
    for (int r = 0; r < 4; ++r) {
      float m = -1e30f;
      #pragma unroll
      for (int jt = 0; jt < 15; ++jt) m = fmaxf(m, acc[jt][r]);
      #pragma unroll
      for (int o = 8; o; o >>= 1) m = fmaxf(m, __shfl_xor(m, o));
      float s = 0.f;
      #pragma unroll
      for (int jt = 0; jt < 15; ++jt) {
        float p = __expf(acc[jt][r] - m);
        if (jt == 14 && c >= 2) p = 0.f;   // j = 224+c >= 226 invalid (dup rows)
        acc[jt][r] = p;
        s += p;
      }
      #pragma unroll
      for (int o = 8; o; o >>= 1) s += __shfl_xor(s, o);
      rinv[r] = 1.f / s;
    }
    ffrag4 oa[4];
    #pragma unroll
    for (int dt = 0; dt < 4; ++dt) oa[dt] = (ffrag4){0.f, 0.f, 0.f, 0.f};
    for (int jc = 0; jc < 8; ++jc) {
      uint16_t* pw = &pb[w][jc & 1][0];   // double-buffer: no WAR across jc
      if (jc == 7) {
        *(unsigned long long*)(pw + c * PBP + 16 + quad * 4) = 0ull;  // zero E cols 16..31
      }
      #pragma unroll
      for (int r = 0; r < 4; ++r) {
        int row = quad * 4 + r;
        pw[row * PBP + c] = f2b(acc[2 * jc][r]);
        if (jc < 7) pw[row * PBP + 16 + c] = f2b(acc[2 * jc + 1][r]);
      }
      bfrag8 pa = *(const bfrag8*)(pw + c * PBP + quad * 8);  // byte 80c+16q: 16B-aligned
      int j0 = jc * 32;
      #pragma unroll
      for (int dt = 0; dt < 4; ++dt) {
        bfrag8 vb;
        if (jc < 7)
          vb = *(const bfrag8*)(vt + (dt * 16 + c) * VP + j0 + quad * 8);
        else
          vb = *(const bfrag8*)(vt + (dt * 16 + c) * VP + 224 + (quad & 1) * 8);
        oa[dt] = __builtin_amdgcn_mfma_f32_16x16x32_bf16(pa, vb, oa[dt], 0, 0, 0);
      }
    }
    #pragma unroll
    for (int dt = 0; dt < 4; ++dt) {
      #pragma unroll
      for (int r = 0; r < 4; ++r) {
        int i = i0 + quad * 4 + r;
        if (i < NTOK)
          Og[((size_t)sb * NTOK + i) * NIN + h * DH + dt * 16 + c] =
              f2b(oa[dt][r] * rinv[r]);
      }
    }
  }
}

// ---- merged proj+FF: 2 waves per 16-row tile — BYTE-EXACT R10 (erff) ----
__global__ __launch_bounds__(128) void k_pf(const uint16_t* __restrict__ Og,
    const uint16_t* __restrict__ Wot,   // [64][512] bf16
    const float* __restrict__ bo, float* __restrict__ X,
    const float* __restrict__ g2, const float* __restrict__ bb2,
    const uint16_t* __restrict__ W1t,   // [256][64] bf16
    const float* __restrict__ b1,
    const uint16_t* __restrict__ W2t,   // [64][256] bf16
    const float* __restrict__ b2,
    const float* __restrict__ gn, const float* __restrict__ bbn,
    uint16_t* __restrict__ XnOut) {
  __shared__ __align__(16) uint16_t xa2[16 * 72];    // 2304 B
  __shared__ __align__(16) uint16_t ha[16 * 264];    // 8448 B
  __shared__ float lnp[2][16][2];                    // 256 B: [wave][row][s,q]
  int t = threadIdx.x;                 // 128 = 2 waves
  int w = t >> 6, l = t & 63;
  int quad = l >> 4, c = l & 15;
  int r0 = blockIdx.x * 16;

  // ---- proj part: wave w computes jt in {2w, 2w+1} ----
  const uint16_t* orow = Og + (size_t)(r0 + c) * 512 + quad * 8;
  bfrag8 a[16];
  #pragma unroll
  for (int kc = 0; kc < 16; ++kc) a[kc] = *(const bfrag8*)(orow + kc * 32);
  ffrag4 acc[2][2];                    // [jt_local][kc parity] -> chains of 8
  #pragma unroll
  for (int j = 0; j < 2; ++j)
    #pragma unroll
    for (int p = 0; p < 2; ++p) acc[j][p] = (ffrag4){0.f, 0.f, 0.f, 0.f};
  #pragma unroll
  for (int kc = 0; kc < 16; ++kc) {
    #pragma unroll
    for (int j = 0; j < 2; ++j) {
      int jt = 2 * w + j;
      bfrag8 b = *(const bfrag8*)(Wot + (size_t)(jt * 16 + c) * 512 + kc * 32 + quad * 8);
      acc[j][kc & 1] = __builtin_amdgcn_mfma_f32_16x16x32_bf16(a[kc], b, acc[j][kc & 1], 0, 0, 0);
    }
  }
  float xv[2][4];
  #pragma unroll
  for (int j = 0; j < 2; ++j) {
    int jt = 2 * w + j;
    float bv = bo[jt * 16 + c];
    #pragma unroll
    for (int r = 0; r < 4; ++r) {
      int il = quad * 4 + r;
      size_t idx = (size_t)(r0 + il) * 64 + jt * 16 + c;
      xv[j][r] = X[idx] + (acc[j][0][r] + acc[j][1][r]) + bv;   // X write deferred to FF2
    }
  }
  #pragma unroll
  for (int r = 0; r < 4; ++r) {
    float s = xv[0][r] + xv[1][r];
    float q = xv[0][r] * xv[0][r] + xv[1][r] * xv[1][r];
    #pragma unroll
    for (int o = 8; o; o >>= 1) { s += __shfl_xor(s, o); q += __shfl_xor(q, o); }
    if (c == 0) { lnp[w][quad * 4 + r][0] = s; lnp[w][quad * 4 + r][1] = q; }
  }
  __syncthreads();
  #pragma unroll
  for (int r = 0; r < 4; ++r) {
    int il = quad * 4 + r;
    float s = lnp[0][il][0] + lnp[1][il][0];
    float q = lnp[0][il][1] + lnp[1][il][1];
    float m = s * (1.f / 64.f);
    float rs = rsqrtf(q * (1.f / 64.f) - m * m + 1e-5f);
    #pragma unroll
    for (int j = 0; j < 2; ++j) {
      int n = (2 * w + j) * 16 + c;
      xa2[il * 72 + n] = f2b((xv[j][r] - m) * rs * g2[n] + bb2[n]);
    }
  }
  __syncthreads();
  // ---- FF1: wave w computes h-cols jt in {8w .. 8w+7} ----
  const uint16_t* xrow = xa2 + c * 72;
  bfrag8 a0 = *(const bfrag8*)(xrow + quad * 8);
  bfrag8 a1 = *(const bfrag8*)(xrow + 32 + quad * 8);
  #pragma unroll
  for (int jj = 0; jj < 8; ++jj) {
    int jt = 8 * w + jj;
    bfrag8 b0  = *(const bfrag8*)(W1t + (size_t)(jt * 16 + c) * 64 + quad * 8);
    bfrag8 b1f = *(const bfrag8*)(W1t + (size_t)(jt * 16 + c) * 64 + 32 + quad * 8);
    ffrag4 z = {0.f, 0.f, 0.f, 0.f};
    z = __builtin_amdgcn_mfma_f32_16x16x32_bf16(a0, b0, z, 0, 0, 0);
    z = __builtin_amdgcn_mfma_f32_16x16x32_bf16(a1, b1f, z, 0, 0, 0);
    float bv = b1[jt * 16 + c];
    #pragma unroll
    for (int r = 0; r < 4; ++r) {
      float zz = z[r] + bv;
      float hg = 0.5f * zz * (1.f + erff(zz * 0.7071067811865476f));
      ha[(quad * 4 + r) * 264 + jt * 16 + c] = f2b(hg);
    }
  }
  __syncthreads();
  // ---- FF2: wave w computes out cols jt in {2w, 2w+1} ----
  ffrag4 o2[2][2];
  #pragma unroll
  for (int j = 0; j < 2; ++j)
    #pragma unroll
    for (int p = 0; p < 2; ++p) o2[j][p] = (ffrag4){0.f, 0.f, 0.f, 0.f};
  #pragma unroll
  for (int kc = 0; kc < 8; ++kc) {
    bfrag8 pa = *(const bfrag8*)(ha + c * 264 + kc * 32 + quad * 8);
    #pragma unroll
    for (int j = 0; j < 2; ++j) {
      int jt = 2 * w + j;
      bfrag8 vb = *(const bfrag8*)(W2t + (size_t)(jt * 16 + c) * 256 + kc * 32 + quad * 8);
      o2[j][kc & 1] = __builtin_amdgcn_mfma_f32_16x16x32_bf16(pa, vb, o2[j][kc & 1], 0, 0, 0);
    }
  }
  float yv[2][4];
  #pragma unroll
  for (int j = 0; j < 2; ++j) {
    int jt = 2 * w + j;
    float bv = b2[jt * 16 + c];
    #pragma unroll
    for (int r = 0; r < 4; ++r) {
      int il = quad * 4 + r;
      size_t idx = (size_t)(r0 + il) * 64 + jt * 16 + c;
      float v = xv[j][r] + (o2[j][0][r] + o2[j][1][r]) + bv;    // residual from regs
      X[idx] = v;
      yv[j][r] = v;
    }
  }
  #pragma unroll
  for (int r = 0; r < 4; ++r) {
    float s = yv[0][r] + yv[1][r];
    float q = yv[0][r] * yv[0][r] + yv[1][r] * yv[1][r];
    #pragma unroll
    for (int o = 8; o; o >>= 1) { s += __shfl_xor(s, o); q += __shfl_xor(q, o); }
    if (c == 0) { lnp[w][quad * 4 + r][0] = s; lnp[w][quad * 4 + r][1] = q; }
  }
  __syncthreads();
  #pragma unroll
  for (int r = 0; r < 4; ++r) {
    int il = quad * 4 + r;
    float s = lnp[0][il][0] + lnp[1][il][0];
    float q = lnp[0][il][1] + lnp[1][il][1];
    float m = s * (1.f / 64.f);
    float rs = rsqrtf(q * (1.f / 64.f) - m * m + 1e-5f);
    #pragma unroll
    for (int j = 0; j < 2; ++j) {
      int n = (2 * w + j) * 16 + c;
      XnOut[(size_t)(r0 + il) * 64 + n] = f2b((yv[j][r] - m) * rs * gn[n] + bbn[n]);
    }
  }
}

// ---- swap cls tokens between streams; refresh Xn (LN1 layer0) for those rows ----
__global__ void k_xchg(float* __restrict__ X, uint16_t* __restrict__ Xn,
                       const float* __restrict__ g, const float* __restrict__ bb) {
  int b = blockIdx.x, d = threadIdx.x;   // 64 blocks x 64 threads (1 wave)
  size_t i0 = (size_t)(b * NTOK) * ND + d;
  size_t i1 = (size_t)((64 + b) * NTOK) * ND + d;
  float a = X[i0], cc = X[i1];
  X[i0] = cc; X[i1] = a;
  float s0 = cc, q0 = cc * cc, s1 = a, q1 = a * a;
  #pragma unroll
  for (int o = 32; o; o >>= 1) {
    s0 += __shfl_xor(s0, o); q0 += __shfl_xor(q0, o);
    s1 += __shfl_xor(s1, o); q1 += __shfl_xor(q1, o);
  }
  float m0 = s0 * (1.f / 64.f), rs0 = rsqrtf(q0 * (1.f / 64.f) - m0 * m0 + 1e-5f);
  float m1 = s1 * (1.f / 64.f), rs1 = rsqrtf(q1 * (1.f / 64.f) - m1 * m1 + 1e-5f);
  Xn[i0] = f2b((cc - m0) * rs0 * g[d] + bb[d]);
  Xn[i1] = f2b((a - m1) * rs1 * g[d] + bb[d]);
}

// ---- final: out = h_cls + l_cls ----
__global__ void k_out(const float* __restrict__ X, float* __restrict__ out) {
  int i = blockIdx.x * 64 + threadIdx.x;
  int b = i >> 6, d = i & 63;
  out[i] = X[(size_t)b * NTOK * ND + d] + X[(size_t)(64 + b) * NTOK * ND + d];
}

extern "C" void kernel_launch(void* const* d_in, const int* in_sizes, int n_in,
                              void* d_out, int out_size, void* d_ws, size_t ws_size,
                              hipStream_t stream) {
  const float* hsi   = (const float*)d_in[0];
  const float* lidar = (const float*)d_in[1];
  const float* cls_h = (const float*)d_in[2];
  const float* cls_l = (const float*)d_in[3];
  const float* pos_h = (const float*)d_in[4];
  const float* pos_l = (const float*)d_in[5];
  const float* fmg_w = (const float*)d_in[6];
  const float* ln1_g = (const float*)d_in[7];
  const float* ln1_b = (const float*)d_in[8];
  const float* qkv_w = (const float*)d_in[9];
  const float* out_w = (const float*)d_in[10];
  const float* out_b = (const float*)d_in[11];
  const float* ln2_g = (const float*)d_in[12];
  const float* ln2_b = (const float*)d_in[13];
  const float* ff_w1 = (const float*)d_in[14];
  const float* ff_b1 = (const float*)d_in[15];
  const float* ff_w2 = (const float*)d_in[16];
  const float* ff_b2 = (const float*)d_in[17];

  char* ws = (char*)d_ws;
  float*    X    = (float*)ws;                       // 7,405,568 B
  float*    sdfm = (float*)(ws + 7405568);           // 16,384 B
  uint16_t* Xn   = (uint16_t*)(ws + 7421952);        // 3,702,784 B
  uint16_t* Og   = (uint16_t*)(ws + 11124736);       // 29,622,272 B
  uint16_t* Wqv  = (uint16_t*)(ws + 40747008);       // 524,288 B
  uint16_t* Wo   = (uint16_t*)(ws + 41271296);       // 262,144 B
  uint16_t* W1   = (uint16_t*)(ws + 41533440);       // 131,072 B
  uint16_t* W2   = (uint16_t*)(ws + 41664512);       // 131,072 B -> end 41,795,584

  k_setup<<<2336, 256, 0, stream>>>(qkv_w, out_w, ff_w1, ff_w2, fmg_w,
                                    hsi, lidar, cls_h, cls_l, pos_h, pos_l,
                                    ln1_g, ln1_b,
                                    Wqv, Wo, W1, W2, sdfm, X, Xn);
  for (int pass = 0; pass < 2; ++pass) {
    for (int ly = 0; ly < NDEPTH; ++ly) {
      int nx = (ly + 1) & 3;   // next layer's LN1 params (harmless on final layer)
      k_fattn<<<NSB * NH, 512, 0, stream>>>(Xn, Wqv + (size_t)ly * 65536, sdfm, Og);
      k_pf<<<NROWS / 16, 128, 0, stream>>>(Og, Wo + (size_t)ly * 32768, out_b + ly * ND,
                                           X, ln2_g + ly * ND, ln2_b + ly * ND,
                                           W1 + (size_t)ly * 16384, ff_b1 + ly * NMLP,
                                           W2 + (size_t)ly * 16384, ff_b2 + ly * ND,
                                           ln1_g + nx * ND, ln1_b + nx * ND, Xn);
    }
    if (pass == 0) k_xchg<<<64, 64, 0, stream>>>(X, Xn, ln1_g, ln1_b);
  }
  k_out<<<64, 64, 0, stream>>>(X, (float*)d_out);
}